// Round 2
// 466.139 us; speedup vs baseline: 1.0077x; 1.0077x over previous
//
#include <hip/hip_runtime.h>
#include <hip/hip_bf16.h>

#define V    100000
#define EMB  128
#define REG  7
#define NC   20
#define ML   512
#define BB   64
#define RAD  3
#define ENT  506      // ML - 2*RAD
#define NBC  64       // chunks of 8 entries per batch row (64*8 = 512 >= 506)

typedef float f32x4 __attribute__((ext_vector_type(4)));

// Kernel 1: 2 entries per wave (half-wave = one entry; 32 lanes x float4 =
// one 512B embedding row slice per load -> 1KB/instruction, fully coalesced).
// W_region rows are single-use -> nontemporal loads (don't evict the 51MB
// W_word table from L3, which IS re-read ~7x per row across blocks).
// partial is write-once/read-once -> nontemporal both sides.
//
// Semantics (reshape trap): E index for (b,i,j) is t=i*7+j;
// word = train[b, (t%506) + (t/506)]; region row = train[b, i+3], slice j.
__global__ __launch_bounds__(256, 4) void noi_kernel(
    const int*   __restrict__ train,
    const float* __restrict__ Wr,
    const float* __restrict__ Ww,
    float*       __restrict__ partial)
{
    __shared__ __align__(16) float red[4][EMB];

    const int b     = blockIdx.y;          // 0..63
    const int chunk = blockIdx.x;          // 0..63 (8 entries each)
    const int tid   = threadIdx.x;
    const int w     = tid >> 6;
    const int lane  = tid & 63;
    const int half  = lane >> 5;           // which entry of the pair
    const int sl    = lane & 31;           // 4-channel group within the row

    const int  i_raw = chunk * 8 + w * 2 + half;
    const bool valid = (i_raw < ENT);
    const int  i     = valid ? i_raw : (ENT - 1);   // clamp; mask result later

    const int* trow = train + b * ML;
    const int  ridx = trow[i + RAD];
    int widx[REG];
    #pragma unroll
    for (int j = 0; j < REG; ++j) {
        const int t = i * REG + j;
        const int r = t / ENT;             // const divisor -> magic mul
        const int e = t - r * ENT;
        widx[j] = trow[e + r];
    }

    const float* Kbase = Wr + (size_t)ridx * (REG * EMB);
    f32x4 kv[REG], ev[REG];
    #pragma unroll
    for (int j = 0; j < REG; ++j) {
        const f32x4* kp = (const f32x4*)(Kbase + j * EMB) + sl;
        kv[j] = __builtin_nontemporal_load(kp);     // single-use rows
    }
    #pragma unroll
    for (int j = 0; j < REG; ++j)
        ev[j] = ((const f32x4*)(Ww + (size_t)widx[j] * EMB))[sl]; // temporal: L3-reused

    f32x4 m = kv[0] * ev[0];
    #pragma unroll
    for (int j = 1; j < REG; ++j) {
        const f32x4 p = kv[j] * ev[j];
        m[0] = fmaxf(m[0], p[0]);
        m[1] = fmaxf(m[1], p[1]);
        m[2] = fmaxf(m[2], p[2]);
        m[3] = fmaxf(m[3], p[3]);
    }
    if (!valid) { m[0] = 0.f; m[1] = 0.f; m[2] = 0.f; m[3] = 0.f; }

    // fold the two entries of the wave (sum over i): lane sl += lane sl+32
    m[0] += __shfl_down(m[0], 32);
    m[1] += __shfl_down(m[1], 32);
    m[2] += __shfl_down(m[2], 32);
    m[3] += __shfl_down(m[3], 32);
    if (half == 0)
        ((f32x4*)red[w])[sl] = m;
    __syncthreads();

    if (tid < EMB) {
        const float s = red[0][tid] + red[1][tid] + red[2][tid] + red[3][tid];
        __builtin_nontemporal_store(
            s, &partial[((size_t)b * NBC + chunk) * EMB + tid]);
    }
}

// Kernel 2: one block of 1024 threads per batch row (16 waves for latency
// hiding). Reduce 64 partials (8-way parallel) -> noi[128];
// h = relu(noi @ W1 + b1): thread t owns column t, W1 reads fully coalesced;
// logits = h @ W2 + b2 (20); softmax + argmax; write logits | prob | cls.
__global__ __launch_bounds__(1024) void mlp_kernel(
    const float* __restrict__ partial,
    const float* __restrict__ W1,
    const float* __restrict__ b1,
    const float* __restrict__ W2,
    const float* __restrict__ b2,
    float*       __restrict__ out)
{
    __shared__ float red2[8][EMB];
    __shared__ float noi[EMB];
    __shared__ float h[2 * ML];
    __shared__ float lg[NC];

    const int b   = blockIdx.x;
    const int tid = threadIdx.x;

    {   // 8 groups of 128 threads, each sums 8 of the 64 partials
        const int col = tid & 127;
        const int grp = tid >> 7;          // 0..7
        const float* p = partial + ((size_t)b * NBC + grp * 8) * EMB + col;
        float s = 0.f;
        #pragma unroll
        for (int k = 0; k < 8; ++k)
            s += __builtin_nontemporal_load(&p[(size_t)k * EMB]);  // read-once
        red2[grp][col] = s;
    }
    __syncthreads();
    if (tid < EMB) {
        float s = 0.f;
        #pragma unroll
        for (int g = 0; g < 8; ++g)
            s += red2[g][tid];
        noi[tid] = s;
    }
    __syncthreads();

    // h: thread t owns column t; W1[k*1024 + t] coalesced across the wave
    float acc = b1[tid];
    #pragma unroll 8
    for (int k = 0; k < EMB; ++k)
        acc = fmaf(noi[k], W1[k * (2 * ML) + tid], acc);
    h[tid] = fmaxf(acc, 0.f);
    __syncthreads();

    // logits: 16 waves; wave w takes classes c = w, w+16; lanes split k
    const int w    = tid >> 6;
    const int lane = tid & 63;
    for (int c = w; c < NC; c += 16) {
        float p = 0.f;
        #pragma unroll
        for (int k = lane; k < 2 * ML; k += 64)
            p = fmaf(h[k], W2[k * NC + c], p);
        for (int off = 32; off; off >>= 1)
            p += __shfl_down(p, off);
        if (lane == 0) lg[c] = p + b2[c];
    }
    __syncthreads();

    if (tid == 0) {
        float mx = lg[0];
        for (int c = 1; c < NC; ++c) mx = fmaxf(mx, lg[c]);
        float pr[NC];
        float s = 0.f;
        for (int c = 0; c < NC; ++c) { pr[c] = __expf(lg[c] - mx); s += pr[c]; }
        const float inv = 1.f / s;
        int am = 0; float best = lg[0];
        for (int c = 1; c < NC; ++c) if (lg[c] > best) { best = lg[c]; am = c; }
        for (int c = 0; c < NC; ++c) {
            out[b * NC + c]           = lg[c];           // logits
            out[BB * NC + b * NC + c] = pr[c] * inv;     // prob
        }
        out[2 * BB * NC + b] = (float)am;                // cls (as float)
    }
}

extern "C" void kernel_launch(void* const* d_in, const int* in_sizes, int n_in,
                              void* d_out, int out_size, void* d_ws, size_t ws_size,
                              hipStream_t stream) {
    const int*   train = (const int*)  d_in[0];
    const float* Wr    = (const float*)d_in[1];
    const float* Ww    = (const float*)d_in[2];
    const float* W1    = (const float*)d_in[3];
    const float* b1    = (const float*)d_in[4];
    const float* W2    = (const float*)d_in[5];
    const float* b2    = (const float*)d_in[6];
    float* out     = (float*)d_out;
    float* partial = (float*)d_ws;     // 64*64*128*4 = 2 MB

    hipLaunchKernelGGL(noi_kernel, dim3(NBC, BB), dim3(256), 0, stream,
                       train, Wr, Ww, partial);
    hipLaunchKernelGGL(mlp_kernel, dim3(BB), dim3(1024), 0, stream,
                       partial, W1, b1, W2, b2, out);
}